// Round 6
// baseline (251.577 us; speedup 1.0000x reference)
//
#include <hip/hip_runtime.h>
#include <stdint.h>

// DCN v1 forward: B=8, C=256, H=W=64, K=3, pad=1, stride=1, O=256.
// Round 9: full revert to the proven R0 structure (best measured: 73us
// dcn_main / 148.8us total). Five structural variants all regressed:
// split-K (occupancy is VGPR-pinned), 2-deep gathers (spill past the
// 128-reg ceiling), 4Mx2N retile (LDS not binding; lost A-dbuf cover),
// ring-4 supersteps (barriers not binding). R0 = local optimum under
// {128 reg, 2 blk/CU, 1-deep pipeline}. Single added lever vs R0:
// T5 s_setprio(1)/(0) around the MFMA cluster. Waves de-sync between
// barriers (gather latency divergence) -> CU scheduler can favor the
// MFMA-entering wave over waves still issuing gathers (attn-like role
// diversity, not m190's lockstep null case). Zero reg/LDS/schedule risk.

#define Bb 8
#define Cc 256
#define Hh 64
#define Ww 64
#define Pp 4096
#define Oo 256
#define NK2 9
#define NPAIR 36             // 36 pairs of K-steps (BK=64 each)
#define BN 64
#define SROW 40              // padded S row stride (elems)
#define WT_BYTES (2u * 72u * 256u * 32u)  // 1,179,648

typedef __attribute__((ext_vector_type(4))) float f32x4;
typedef __attribute__((ext_vector_type(8))) short s16x8;
typedef __attribute__((ext_vector_type(4))) int   i32x4;

static __device__ __forceinline__ unsigned short f2bf(float f) {
    union { float f; uint32_t u; } v; v.f = f;
    return (unsigned short)((v.u + 0x7fffu + ((v.u >> 16) & 1u)) >> 16);  // RNE
}
static __device__ __forceinline__ int imin(int a, int b) { return a < b ? a : b; }
static __device__ __forceinline__ int imax(int a, int b) { return a > b ? a : b; }

// ---------------- fused prep: x-transpose (blocks 0..2047) + weight (2048..2111)
// xT[b][p][c] bf16 ; wt[ks(72)][oc(256)][c32(32)] bf16, ks = k2*8+cch.
__global__ __launch_bounds__(256)
void prep(const float* __restrict__ x, const float* __restrict__ w,
          unsigned short* __restrict__ xt, unsigned short* __restrict__ wt) {
    __shared__ __align__(16) unsigned short L[9216];   // 18 KB, dual-purpose
    const int bx = blockIdx.x, tid = threadIdx.x;

    if (bx < 2048) {
        // ---- x: tile 64 c x 64 px ; b = bx&7 keeps XCD affinity with dcn_main
        unsigned short (*t2)[72] = (unsigned short(*)[72])L;  // 64 x 72 shorts
        const int b = bx & 7, ti = bx >> 3;
        const int c0 = (ti & 3) * 64, p0 = (ti >> 2) * 64;
        #pragma unroll
        for (int rd = 0; rd < 4; rd++) {
            int c = (tid >> 4) + rd * 16;
            int px4 = (tid & 15) * 4;
            f32x4 fv = *(const f32x4*)&x[(size_t)(b * Cc + c0 + c) * Pp + p0 + px4];
            #pragma unroll
            for (int j = 0; j < 4; j++) {
                int px = px4 + j;
                int chunk = ((c >> 3) + px) & 7;      // rotate chunks to spread banks
                t2[px][chunk * 8 + (c & 7)] = f2bf(fv[j]);
            }
        }
        __syncthreads();
        #pragma unroll
        for (int rd = 0; rd < 2; rd++) {
            int px = (tid >> 3) + rd * 32;
            int k = tid & 7;
            int chunk = (k + px) & 7;
            uint4 u = *(const uint4*)&t2[px][chunk * 8];
            *(uint4*)&xt[(size_t)(b * Pp + p0 + px) * Cc + c0 + k * 8] = u;
        }
    } else {
        // ---- weight: 64 blocks x 4 o-rows
        const int o0 = (bx - 2048) * 4;
        #pragma unroll
        for (int r9 = 0; r9 < 9; r9++) {
            int idx = r9 * 256 + tid;                  // 0..2303 float4s over 4 rows
            f32x4 fv = *(const f32x4*)&w[(size_t)o0 * 2304 + (size_t)idx * 4];
            #pragma unroll
            for (int j = 0; j < 4; j++) L[idx * 4 + j] = f2bf(fv[j]);
        }
        __syncthreads();
        #pragma unroll 4
        for (int i = 0; i < 36; i++) {
            int ks = i * 2 + (tid >> 7);
            int r = (tid >> 5) & 3, c32 = tid & 31;
            int c = (ks & 7) * 32 + c32, k2 = ks >> 3;
            wt[(size_t)ks * 8192 + (o0 + r) * 32 + c32] = L[r * 2304 + c * 9 + k2];
        }
    }
}

// ---------------- fused sampler + GEMM, software-pipelined (R0 schedule).
// Block: 512 thr = 8 waves, each wave 32(M) x 64(N). Grid: 512 flat, b = bx&7.
__global__ __launch_bounds__(512, 4)
void dcn_main(const float* __restrict__ off, const unsigned short* __restrict__ wt,
              const unsigned short* __restrict__ xt, float* __restrict__ out) {
    __shared__ __align__(16) unsigned short Sl[2][2][BN][SROW];  // 20480 B
    __shared__ __align__(16) int   tidx[NK2][BN][4];             // 9216 B (byte offs)
    __shared__ __align__(16) float twgt[NK2][BN][4];             // 9216 B

    const int b   = blockIdx.x & 7;
    const int p0  = (blockIdx.x >> 3) * BN;
    const int tid = threadIdx.x;
    const int lane = tid & 63;
    const int wv   = tid >> 6;
    const int quad = lane >> 4;
    const int l16  = lane & 15;
    const int moff = wv * 32;

    const int px  = tid >> 3;          // sampler: 8 threads/pixel
    const int sub = tid & 7;
    const int hh_ = sub >> 2;
    const int cc_ = (sub & 3) * 8;

    const char* xtb = (const char*)xt + (size_t)b * Pp * Cc * 2;

    // ---- taps for all 9 kernel points ----
    for (int t = tid; t < NK2 * BN; t += 512) {
        int k2 = t >> 6, pxl = t & 63;
        int pl = p0 + pxl;
        int hh = pl >> 6, ww = pl & 63;
        int ky = k2 / 3, kx = k2 - ky * 3;
        float dy = off[((size_t)(b * 18 + 2 * k2    ) * Pp) + pl];
        float dx = off[((size_t)(b * 18 + 2 * k2 + 1) * Pp) + pl];
        float py  = (float)(hh - 1 + ky) + dy;
        float pxf = (float)(ww - 1 + kx) + dx;
        float y0f = floorf(py), x0f = floorf(pxf);
        int   y0 = (int)y0f,  x0 = (int)x0f;
        int   y1 = y0 + 1,    x1 = x0 + 1;
        float ly = py - y0f,  lx = pxf - x0f;
        float oy = 1.f - ly,  ox = 1.f - lx;
        bool vy0 = (y0 >= 0) && (y0 < Hh);
        bool vy1 = (y1 >= 0) && (y1 < Hh);
        bool vx0 = (x0 >= 0) && (x0 < Ww);
        bool vx1 = (x1 >= 0) && (x1 < Ww);
        int cy0 = imin(imax(y0, 0), Hh - 1), cy1 = imin(imax(y1, 0), Hh - 1);
        int cx0 = imin(imax(x0, 0), Ww - 1), cx1 = imin(imax(x1, 0), Ww - 1);
        i32x4 ti; f32x4 tw;
        ti[0] = (cy0 * Ww + cx0) * 512;  tw[0] = (vy0 && vx0) ? oy * ox : 0.f;
        ti[1] = (cy0 * Ww + cx1) * 512;  tw[1] = (vy0 && vx1) ? oy * lx : 0.f;
        ti[2] = (cy1 * Ww + cx0) * 512;  tw[2] = (vy1 && vx0) ? ly * ox : 0.f;
        ti[3] = (cy1 * Ww + cx1) * 512;  tw[3] = (vy1 && vx1) ? ly * lx : 0.f;
        *(i32x4*)&tidx[k2][pxl][0] = ti;
        *(f32x4*)&twgt[k2][pxl][0] = tw;
    }
    __syncthreads();

    int   tio[4];
    float twv[4];
    uint4 g[4];
    {
        i32x4 ti = *(const i32x4*)&tidx[0][px][0];
        f32x4 tw = *(const f32x4*)&twgt[0][px][0];
        #pragma unroll
        for (int t = 0; t < 4; t++) { tio[t] = ti[t]; twv[t] = tw[t]; }
    }

    f32x4 acc[2][4];
    #pragma unroll
    for (int mt = 0; mt < 2; mt++)
        #pragma unroll
        for (int nt = 0; nt < 4; nt++) acc[mt][nt] = (f32x4){0.f, 0.f, 0.f, 0.f};

    // reduce gathered taps (in g) -> pack bf16 -> store into Sl[prn&1]
    auto reduce_store = [&](int prn) {
        float s0 = 0.f, s1 = 0.f, s2 = 0.f, s3 = 0.f, s4 = 0.f, s5 = 0.f, s6 = 0.f, s7 = 0.f;
        #pragma unroll
        for (int t = 0; t < 4; t++) {
            uint4 v = g[t];
            float wg = twv[t];
            s0 += wg * __uint_as_float(v.x << 16);
            s1 += wg * __uint_as_float(v.x);          // low bits = mantissa noise <2^-8
            s2 += wg * __uint_as_float(v.y << 16);
            s3 += wg * __uint_as_float(v.y);
            s4 += wg * __uint_as_float(v.z << 16);
            s5 += wg * __uint_as_float(v.z);
            s6 += wg * __uint_as_float(v.w << 16);
            s7 += wg * __uint_as_float(v.w);
        }
        uint4 d;
        d.x = __builtin_amdgcn_perm(__float_as_uint(s1), __float_as_uint(s0), 0x07060302u);
        d.y = __builtin_amdgcn_perm(__float_as_uint(s3), __float_as_uint(s2), 0x07060302u);
        d.z = __builtin_amdgcn_perm(__float_as_uint(s5), __float_as_uint(s4), 0x07060302u);
        d.w = __builtin_amdgcn_perm(__float_as_uint(s7), __float_as_uint(s6), 0x07060302u);
        *(uint4*)&Sl[prn & 1][hh_][px][cc_] = d;
    };

    s16x8 afA[2][2], afB[2][2];

    // one pipelined K-pair step: consume `cur` + Sl[pr&1]; prefetch pair pr+1
    auto step = [&](int pr, s16x8 (&cur)[2][2], s16x8 (&nxt)[2][2]) {
        __syncthreads();                       // Sl[pr&1] now visible
        const int prn = pr + 1;
        if (prn < NPAIR) {
            if ((prn & 3) == 0) {              // new kernel point: reload taps
                int k2 = prn >> 2;
                i32x4 ti = *(const i32x4*)&tidx[k2][px][0];
                f32x4 tw = *(const f32x4*)&twgt[k2][px][0];
                #pragma unroll
                for (int t = 0; t < 4; t++) { tio[t] = ti[t]; twv[t] = tw[t]; }
            }
            const int coff = (prn & 3) * 128 + sub * 16;
            #pragma unroll
            for (int t = 0; t < 4; t++)        // gathers first (oldest in vm queue)
                g[t] = *(const uint4*)(xtb + tio[t] + coff);
            const char* wb = (const char*)wt + ((size_t)prn << 15);
            #pragma unroll
            for (int h = 0; h < 2; h++)        // A-prefetch for pr+1
                #pragma unroll
                for (int mt = 0; mt < 2; mt++)
                    nxt[h][mt] = *(const s16x8*)(wb + h * 16384 +
                                                 (moff + mt * 16 + l16) * 64 + quad * 16);
        }
        // B fragments + MFMA on current buffer (overlaps the loads above)
        s16x8 bfr[2][4];
        const char* sb = (const char*)&Sl[pr & 1][0][0][0];
        #pragma unroll
        for (int h = 0; h < 2; h++)
            #pragma unroll
            for (int nt = 0; nt < 4; nt++)
                bfr[h][nt] = *(const s16x8*)(sb + h * (BN * SROW * 2) +
                                             (nt * 16 + l16) * (SROW * 2) + quad * 16);
        __builtin_amdgcn_s_setprio(1);         // T5: favor MFMA-entering wave
        #pragma unroll
        for (int h = 0; h < 2; h++)
            #pragma unroll
            for (int mt = 0; mt < 2; mt++)
                #pragma unroll
                for (int nt = 0; nt < 4; nt++)
                    acc[mt][nt] = __builtin_amdgcn_mfma_f32_16x16x32_bf16(
                        cur[h][mt], bfr[h][nt], acc[mt][nt], 0, 0, 0);
        __builtin_amdgcn_s_setprio(0);
        if (prn < NPAIR) reduce_store(prn);    // waits on gathers only
    };

    // preamble: gathers + A for pair 0; build Sl[0]
    {
        #pragma unroll
        for (int t = 0; t < 4; t++)
            g[t] = *(const uint4*)(xtb + tio[t] + sub * 16);
        const char* wb = (const char*)wt;
        #pragma unroll
        for (int h = 0; h < 2; h++)
            #pragma unroll
            for (int mt = 0; mt < 2; mt++)
                afA[h][mt] = *(const s16x8*)(wb + h * 16384 +
                                             (moff + mt * 16 + l16) * 64 + quad * 16);
        reduce_store(0);
    }

    for (int pr = 0; pr < NPAIR; pr += 2) {
        step(pr,     afA, afB);
        step(pr + 1, afB, afA);
    }

    // epilogue: C/D layout row(m)=quad*4+r, col(n)=l16
    float* op = out + ((size_t)b * Oo) * Pp + p0;
    #pragma unroll
    for (int mt = 0; mt < 2; mt++)
        #pragma unroll
        for (int nt = 0; nt < 4; nt++)
            #pragma unroll
            for (int r = 0; r < 4; r++) {
                int o_ = moff + mt * 16 + quad * 4 + r;
                int p_ = nt * 16 + l16;
                op[(size_t)o_ * Pp + p_] = acc[mt][nt][r];
            }
}

extern "C" void kernel_launch(void* const* d_in, const int* in_sizes, int n_in,
                              void* d_out, int out_size, void* d_ws, size_t ws_size,
                              hipStream_t stream) {
    (void)in_sizes; (void)n_in; (void)out_size; (void)ws_size;
    const float* x   = (const float*)d_in[0];
    const float* off = (const float*)d_in[1];
    const float* w   = (const float*)d_in[2];
    float* out = (float*)d_out;

    unsigned short* wt = (unsigned short*)d_ws;
    unsigned short* xt = (unsigned short*)((char*)d_ws + WT_BYTES);

    hipLaunchKernelGGL(prep, dim3(2112), dim3(256), 0, stream, x, w, xt, wt);
    hipLaunchKernelGGL(dcn_main, dim3(512), dim3(512), 0, stream, off, wt, xt, out);
}

// Round 7
// 160.720 us; speedup vs baseline: 1.5653x; 1.5653x over previous
//
#include <hip/hip_runtime.h>
#include <stdint.h>

// DCN v1 forward: B=8, C=256, H=W=64, K=3, pad=1, stride=1, O=256.
// Round 10. Ledger: R0 (73us dcn_main) is a tight local optimum under
// {launch_bounds(512,4) => 128 reg/thread, 2 blk/CU}. Every variant that
// added live state (R3 2-deep gathers, R6 setprio-as-sched-barrier) spilled
// to scratch (WRITE_SIZE 311-546MB signature); every variant that traded
// away a cover (R4 lost A-dbuf, R5 ring-4) regressed; split-K (R1) showed
// occupancy is VGPR-pinned, not grid-pinned. This round removes the ceiling
// instead of working under it: __launch_bounds__(512,2) => 256 VGPR/thread
// budget, 1 block/CU (8 waves). The R3 2-deep gather pipeline (correctness-
// verified) becomes register-resident (~150 regs, no spill): gathers for
// pair pr+2 issue at step pr, consumed at pr+1 => a full step (~600-1000cy)
// of latency cover, and the per-step barrier no longer forces a vmcnt drain
// (in-flight gathers span it). Source = R3 byte-for-byte except the
// launch-bounds annotation and this comment.

#define Bb 8
#define Cc 256
#define Hh 64
#define Ww 64
#define Pp 4096
#define Oo 256
#define NK2 9
#define NPAIR 36             // 36 pairs of K-steps (BK=64 each)
#define BN 64
#define SROW 40              // padded S row stride (elems)
#define WT_BYTES (2u * 72u * 256u * 32u)  // 1,179,648

typedef __attribute__((ext_vector_type(4))) float f32x4;
typedef __attribute__((ext_vector_type(8))) short s16x8;
typedef __attribute__((ext_vector_type(4))) int   i32x4;

static __device__ __forceinline__ unsigned short f2bf(float f) {
    union { float f; uint32_t u; } v; v.f = f;
    return (unsigned short)((v.u + 0x7fffu + ((v.u >> 16) & 1u)) >> 16);  // RNE
}
static __device__ __forceinline__ int imin(int a, int b) { return a < b ? a : b; }
static __device__ __forceinline__ int imax(int a, int b) { return a > b ? a : b; }

// ---------------- fused prep: x-transpose (blocks 0..2047) + weight (2048..2111)
// xT[b][p][c] bf16 ; wt[ks(72)][oc(256)][c32(32)] bf16, ks = k2*8+cch.
__global__ __launch_bounds__(256)
void prep(const float* __restrict__ x, const float* __restrict__ w,
          unsigned short* __restrict__ xt, unsigned short* __restrict__ wt) {
    __shared__ __align__(16) unsigned short L[9216];   // 18 KB, dual-purpose
    const int bx = blockIdx.x, tid = threadIdx.x;

    if (bx < 2048) {
        // ---- x: tile 64 c x 64 px ; b = bx&7 keeps XCD affinity with dcn_main
        unsigned short (*t2)[72] = (unsigned short(*)[72])L;  // 64 x 72 shorts
        const int b = bx & 7, ti = bx >> 3;
        const int c0 = (ti & 3) * 64, p0 = (ti >> 2) * 64;
        #pragma unroll
        for (int rd = 0; rd < 4; rd++) {
            int c = (tid >> 4) + rd * 16;
            int px4 = (tid & 15) * 4;
            f32x4 fv = *(const f32x4*)&x[(size_t)(b * Cc + c0 + c) * Pp + p0 + px4];
            #pragma unroll
            for (int j = 0; j < 4; j++) {
                int px = px4 + j;
                int chunk = ((c >> 3) + px) & 7;      // rotate chunks to spread banks
                t2[px][chunk * 8 + (c & 7)] = f2bf(fv[j]);
            }
        }
        __syncthreads();
        #pragma unroll
        for (int rd = 0; rd < 2; rd++) {
            int px = (tid >> 3) + rd * 32;
            int k = tid & 7;
            int chunk = (k + px) & 7;
            uint4 u = *(const uint4*)&t2[px][chunk * 8];
            *(uint4*)&xt[(size_t)(b * Pp + p0 + px) * Cc + c0 + k * 8] = u;
        }
    } else {
        // ---- weight: 64 blocks x 4 o-rows
        const int o0 = (bx - 2048) * 4;
        #pragma unroll
        for (int r9 = 0; r9 < 9; r9++) {
            int idx = r9 * 256 + tid;                  // 0..2303 float4s over 4 rows
            f32x4 fv = *(const f32x4*)&w[(size_t)o0 * 2304 + (size_t)idx * 4];
            #pragma unroll
            for (int j = 0; j < 4; j++) L[idx * 4 + j] = f2bf(fv[j]);
        }
        __syncthreads();
        #pragma unroll 4
        for (int i = 0; i < 36; i++) {
            int ks = i * 2 + (tid >> 7);
            int r = (tid >> 5) & 3, c32 = tid & 31;
            int c = (ks & 7) * 32 + c32, k2 = ks >> 3;
            wt[(size_t)ks * 8192 + (o0 + r) * 32 + c32] = L[r * 2304 + c * 9 + k2];
        }
    }
}

// ---------------- fused sampler + GEMM, 2-deep software pipeline.
// Block: 512 thr = 8 waves, each wave 32(M) x 64(N). Grid: 512 flat, b = bx&7.
// launch_bounds(512,2): 256-VGPR budget, 1 block/CU -> pipeline fits in regs.
__global__ __launch_bounds__(512, 2)
void dcn_main(const float* __restrict__ off, const unsigned short* __restrict__ wt,
              const unsigned short* __restrict__ xt, float* __restrict__ out) {
    __shared__ __align__(16) unsigned short Sl[2][2][BN][SROW];  // 20480 B
    __shared__ __align__(16) int   tidx[NK2][BN][4];             // 9216 B (byte offs)
    __shared__ __align__(16) float twgt[NK2][BN][4];             // 9216 B

    const int b   = blockIdx.x & 7;
    const int p0  = (blockIdx.x >> 3) * BN;
    const int tid = threadIdx.x;
    const int lane = tid & 63;
    const int wv   = tid >> 6;
    const int quad = lane >> 4;
    const int l16  = lane & 15;
    const int moff = wv * 32;

    const int px  = tid >> 3;          // sampler: 8 threads/pixel
    const int sub = tid & 7;
    const int hh_ = sub >> 2;
    const int cc_ = (sub & 3) * 8;

    const char* xtb = (const char*)xt + (size_t)b * Pp * Cc * 2;

    // ---- taps for all 9 kernel points (b128 vector stores) ----
    for (int t = tid; t < NK2 * BN; t += 512) {
        int k2 = t >> 6, pxl = t & 63;
        int pl = p0 + pxl;
        int hh = pl >> 6, ww = pl & 63;
        int ky = k2 / 3, kx = k2 - ky * 3;
        float dy = off[((size_t)(b * 18 + 2 * k2    ) * Pp) + pl];
        float dx = off[((size_t)(b * 18 + 2 * k2 + 1) * Pp) + pl];
        float py  = (float)(hh - 1 + ky) + dy;
        float pxf = (float)(ww - 1 + kx) + dx;
        float y0f = floorf(py), x0f = floorf(pxf);
        int   y0 = (int)y0f,  x0 = (int)x0f;
        int   y1 = y0 + 1,    x1 = x0 + 1;
        float ly = py - y0f,  lx = pxf - x0f;
        float oy = 1.f - ly,  ox = 1.f - lx;
        bool vy0 = (y0 >= 0) && (y0 < Hh);
        bool vy1 = (y1 >= 0) && (y1 < Hh);
        bool vx0 = (x0 >= 0) && (x0 < Ww);
        bool vx1 = (x1 >= 0) && (x1 < Ww);
        int cy0 = imin(imax(y0, 0), Hh - 1), cy1 = imin(imax(y1, 0), Hh - 1);
        int cx0 = imin(imax(x0, 0), Ww - 1), cx1 = imin(imax(x1, 0), Ww - 1);
        i32x4 ti; f32x4 tw;
        ti[0] = (cy0 * Ww + cx0) * 512;  tw[0] = (vy0 && vx0) ? oy * ox : 0.f;
        ti[1] = (cy0 * Ww + cx1) * 512;  tw[1] = (vy0 && vx1) ? oy * lx : 0.f;
        ti[2] = (cy1 * Ww + cx0) * 512;  tw[2] = (vy1 && vx0) ? ly * ox : 0.f;
        ti[3] = (cy1 * Ww + cx1) * 512;  tw[3] = (vy1 && vx1) ? ly * lx : 0.f;
        *(i32x4*)&tidx[k2][pxl][0] = ti;
        *(f32x4*)&twgt[k2][pxl][0] = tw;
    }
    __syncthreads();

    // two gather chains (even pairs -> A, odd pairs -> B)
    int   tioA[4], tioB[4];
    float twA[4],  twB[4];
    uint4 gA[4],   gB[4];

    f32x4 acc[2][4];
    #pragma unroll
    for (int mt = 0; mt < 2; mt++)
        #pragma unroll
        for (int nt = 0; nt < 4; nt++) acc[mt][nt] = (f32x4){0.f, 0.f, 0.f, 0.f};

    // issue gathers for pair p into chain (g, tio, twv). Chain handles pairs
    // p, p+2, ...; k2 (=p>>2) changes on the chain exactly when (p&2)==0.
    auto issue = [&](int p, uint4 (&g)[4], int (&tio)[4], float (&twv)[4]) {
        if ((p & 2) == 0) {
            int k2 = p >> 2;
            i32x4 ti = *(const i32x4*)&tidx[k2][px][0];
            f32x4 tw = *(const f32x4*)&twgt[k2][px][0];
            #pragma unroll
            for (int t = 0; t < 4; t++) { tio[t] = ti[t]; twv[t] = tw[t]; }
        }
        const int coff = (p & 3) * 128 + sub * 16;
        #pragma unroll
        for (int t = 0; t < 4; t++)
            g[t] = *(const uint4*)(xtb + tio[t] + coff);
    };

    auto loadA = [&](int p, s16x8 (&dst)[2][2]) {
        const char* wb = (const char*)wt + ((size_t)p << 15);
        #pragma unroll
        for (int h = 0; h < 2; h++)
            #pragma unroll
            for (int mt = 0; mt < 2; mt++)
                dst[h][mt] = *(const s16x8*)(wb + h * 16384 +
                                             (moff + mt * 16 + l16) * 64 + quad * 16);
    };

    // reduce gathered taps -> pack bf16 -> store into Sl[prn&1]
    auto reduce_store = [&](int prn, uint4 (&g)[4], float (&twv)[4]) {
        float s0 = 0.f, s1 = 0.f, s2 = 0.f, s3 = 0.f, s4 = 0.f, s5 = 0.f, s6 = 0.f, s7 = 0.f;
        #pragma unroll
        for (int t = 0; t < 4; t++) {
            uint4 v = g[t];
            float wg = twv[t];
            s0 += wg * __uint_as_float(v.x << 16);
            s1 += wg * __uint_as_float(v.x);          // low bits = mantissa noise <2^-8
            s2 += wg * __uint_as_float(v.y << 16);
            s3 += wg * __uint_as_float(v.y);
            s4 += wg * __uint_as_float(v.z << 16);
            s5 += wg * __uint_as_float(v.z);
            s6 += wg * __uint_as_float(v.w << 16);
            s7 += wg * __uint_as_float(v.w);
        }
        uint4 d;
        d.x = __builtin_amdgcn_perm(__float_as_uint(s1), __float_as_uint(s0), 0x07060302u);
        d.y = __builtin_amdgcn_perm(__float_as_uint(s3), __float_as_uint(s2), 0x07060302u);
        d.z = __builtin_amdgcn_perm(__float_as_uint(s5), __float_as_uint(s4), 0x07060302u);
        d.w = __builtin_amdgcn_perm(__float_as_uint(s7), __float_as_uint(s6), 0x07060302u);
        *(uint4*)&Sl[prn & 1][hh_][px][cc_] = d;
    };

    s16x8 afA[2][2], afB[2][2];

    // one pipelined step: consume Sl[pr&1] with A-frags `cur`;
    // issue gathers for pr+2 (2-deep); prefetch A for pr+1; reduce pr+1's
    // gathers (issued one full step ago) into Sl[(pr+1)&1].
    auto step = [&](int pr, s16x8 (&cur)[2][2], s16x8 (&nxt)[2][2],
                    uint4 (&gIss)[4], int (&tioIss)[4], float (&twIss)[4],
                    uint4 (&gRed)[4], float (&twRed)[4]) {
        __syncthreads();                       // Sl[pr&1] now visible
        const int pi = pr + 2;
        if (pi < NPAIR) issue(pi, gIss, tioIss, twIss);
        const int pn = pr + 1;
        if (pn < NPAIR) loadA(pn, nxt);        // A-prefetch for pr+1
        // B fragments + MFMA on current buffer (overlaps the loads above;
        // MFMA's vmcnt wait on `cur` also drains gRed, which is older)
        s16x8 bfr[2][4];
        const char* sb = (const char*)&Sl[pr & 1][0][0][0];
        #pragma unroll
        for (int h = 0; h < 2; h++)
            #pragma unroll
            for (int nt = 0; nt < 4; nt++)
                bfr[h][nt] = *(const s16x8*)(sb + h * (BN * SROW * 2) +
                                             (nt * 16 + l16) * (SROW * 2) + quad * 16);
        #pragma unroll
        for (int h = 0; h < 2; h++)
            #pragma unroll
            for (int mt = 0; mt < 2; mt++)
                #pragma unroll
                for (int nt = 0; nt < 4; nt++)
                    acc[mt][nt] = __builtin_amdgcn_mfma_f32_16x16x32_bf16(
                        cur[h][mt], bfr[h][nt], acc[mt][nt], 0, 0, 0);
        if (pn < NPAIR) reduce_store(pn, gRed, twRed);
    };

    // preamble: gathers for pairs 0 (chain A) and 1 (chain B); A-frags for
    // pair 0; build Sl[0] from chain A.
    issue(0, gA, tioA, twA);
    issue(1, gB, tioB, twB);
    loadA(0, afA);
    reduce_store(0, gA, twA);

    for (int pr = 0; pr < NPAIR; pr += 2) {
        step(pr,     afA, afB, gA, tioA, twA, gB, twB);
        step(pr + 1, afB, afA, gB, tioB, twB, gA, twA);
    }

    // epilogue: C/D layout row(m)=quad*4+r, col(n)=l16
    float* op = out + ((size_t)b * Oo) * Pp + p0;
    #pragma unroll
    for (int mt = 0; mt < 2; mt++)
        #pragma unroll
        for (int nt = 0; nt < 4; nt++)
            #pragma unroll
            for (int r = 0; r < 4; r++) {
                int o_ = moff + mt * 16 + quad * 4 + r;
                int p_ = nt * 16 + l16;
                op[(size_t)o_ * Pp + p_] = acc[mt][nt][r];
            }
}

extern "C" void kernel_launch(void* const* d_in, const int* in_sizes, int n_in,
                              void* d_out, int out_size, void* d_ws, size_t ws_size,
                              hipStream_t stream) {
    (void)in_sizes; (void)n_in; (void)out_size; (void)ws_size;
    const float* x   = (const float*)d_in[0];
    const float* off = (const float*)d_in[1];
    const float* w   = (const float*)d_in[2];
    float* out = (float*)d_out;

    unsigned short* wt = (unsigned short*)d_ws;
    unsigned short* xt = (unsigned short*)((char*)d_ws + WT_BYTES);

    hipLaunchKernelGGL(prep, dim3(2112), dim3(256), 0, stream, x, w, xt, wt);
    hipLaunchKernelGGL(dcn_main, dim3(512), dim3(512), 0, stream, off, wt, xt, out);
}

// Round 8
// 152.135 us; speedup vs baseline: 1.6536x; 1.0564x over previous
//
#include <hip/hip_runtime.h>
#include <stdint.h>

// DCN v1 forward: B=8, C=256, H=W=64, K=3, pad=1, stride=1, O=256.
// Round 11. R7 taught the structural lesson: __syncthreads() lowers to
// s_waitcnt vmcnt(0) lgkmcnt(0) + s_barrier -- the FULL VMEM DRAIN at every
// step barrier force-completes all in-flight gathers/A-prefetches, which is
// why every pipeline-depth experiment (R3 depth-2 spilled, R7 depth-2 at
// (512,2) reg-resident but 1 blk/CU) failed to add cover: depth cannot span
// a drain. Fix (T4, the verified 8-phase-template pattern): replace both
// __syncthreads() in dcn_main with {s_waitcnt lgkmcnt(0); raw s_barrier}.
// LDS ordering (Sl dbuf + taps) only needs lgkm retire: each wave's Sl
// ds_reads/ds_writes are lgkm ops retired by its own lgkmcnt(0) before it
// can pass the barrier that permits the opposite-parity overwrite. Global
// gathers/A-loads land in registers, consumed same-thread -- the compiler
// already inserts counted vmcnt(N) before each use; they now genuinely stay
// in flight across the barrier. Everything else byte-identical to R0
// (73us dcn_main): (512,4), depth-1 gathers, afA/afB dbuf, Sl ring-2.

#define Bb 8
#define Cc 256
#define Hh 64
#define Ww 64
#define Pp 4096
#define Oo 256
#define NK2 9
#define NPAIR 36             // 36 pairs of K-steps (BK=64 each)
#define BN 64
#define SROW 40              // padded S row stride (elems)
#define WT_BYTES (2u * 72u * 256u * 32u)  // 1,179,648

typedef __attribute__((ext_vector_type(4))) float f32x4;
typedef __attribute__((ext_vector_type(8))) short s16x8;
typedef __attribute__((ext_vector_type(4))) int   i32x4;

static __device__ __forceinline__ unsigned short f2bf(float f) {
    union { float f; uint32_t u; } v; v.f = f;
    return (unsigned short)((v.u + 0x7fffu + ((v.u >> 16) & 1u)) >> 16);  // RNE
}
static __device__ __forceinline__ int imin(int a, int b) { return a < b ? a : b; }
static __device__ __forceinline__ int imax(int a, int b) { return a > b ? a : b; }

// barrier that orders LDS only: lgkm retire + raw s_barrier, NO vmcnt drain.
static __device__ __forceinline__ void barrier_lds() {
    asm volatile("s_waitcnt lgkmcnt(0)" ::: "memory");
    __builtin_amdgcn_s_barrier();
}

// ---------------- fused prep: x-transpose (blocks 0..2047) + weight (2048..2111)
// xT[b][p][c] bf16 ; wt[ks(72)][oc(256)][c32(32)] bf16, ks = k2*8+cch.
__global__ __launch_bounds__(256)
void prep(const float* __restrict__ x, const float* __restrict__ w,
          unsigned short* __restrict__ xt, unsigned short* __restrict__ wt) {
    __shared__ __align__(16) unsigned short L[9216];   // 18 KB, dual-purpose
    const int bx = blockIdx.x, tid = threadIdx.x;

    if (bx < 2048) {
        // ---- x: tile 64 c x 64 px ; b = bx&7 keeps XCD affinity with dcn_main
        unsigned short (*t2)[72] = (unsigned short(*)[72])L;  // 64 x 72 shorts
        const int b = bx & 7, ti = bx >> 3;
        const int c0 = (ti & 3) * 64, p0 = (ti >> 2) * 64;
        #pragma unroll
        for (int rd = 0; rd < 4; rd++) {
            int c = (tid >> 4) + rd * 16;
            int px4 = (tid & 15) * 4;
            f32x4 fv = *(const f32x4*)&x[(size_t)(b * Cc + c0 + c) * Pp + p0 + px4];
            #pragma unroll
            for (int j = 0; j < 4; j++) {
                int px = px4 + j;
                int chunk = ((c >> 3) + px) & 7;      // rotate chunks to spread banks
                t2[px][chunk * 8 + (c & 7)] = f2bf(fv[j]);
            }
        }
        __syncthreads();
        #pragma unroll
        for (int rd = 0; rd < 2; rd++) {
            int px = (tid >> 3) + rd * 32;
            int k = tid & 7;
            int chunk = (k + px) & 7;
            uint4 u = *(const uint4*)&t2[px][chunk * 8];
            *(uint4*)&xt[(size_t)(b * Pp + p0 + px) * Cc + c0 + k * 8] = u;
        }
    } else {
        // ---- weight: 64 blocks x 4 o-rows
        const int o0 = (bx - 2048) * 4;
        #pragma unroll
        for (int r9 = 0; r9 < 9; r9++) {
            int idx = r9 * 256 + tid;                  // 0..2303 float4s over 4 rows
            f32x4 fv = *(const f32x4*)&w[(size_t)o0 * 2304 + (size_t)idx * 4];
            #pragma unroll
            for (int j = 0; j < 4; j++) L[idx * 4 + j] = f2bf(fv[j]);
        }
        __syncthreads();
        #pragma unroll 4
        for (int i = 0; i < 36; i++) {
            int ks = i * 2 + (tid >> 7);
            int r = (tid >> 5) & 3, c32 = tid & 31;
            int c = (ks & 7) * 32 + c32, k2 = ks >> 3;
            wt[(size_t)ks * 8192 + (o0 + r) * 32 + c32] = L[r * 2304 + c * 9 + k2];
        }
    }
}

// ---------------- fused sampler + GEMM, software-pipelined (R0 schedule,
// LDS-only barriers). Block: 512 thr = 8 waves, each wave 32(M) x 64(N).
// Grid: 512 flat, b = bx&7.
__global__ __launch_bounds__(512, 4)
void dcn_main(const float* __restrict__ off, const unsigned short* __restrict__ wt,
              const unsigned short* __restrict__ xt, float* __restrict__ out) {
    __shared__ __align__(16) unsigned short Sl[2][2][BN][SROW];  // 20480 B
    __shared__ __align__(16) int   tidx[NK2][BN][4];             // 9216 B (byte offs)
    __shared__ __align__(16) float twgt[NK2][BN][4];             // 9216 B

    const int b   = blockIdx.x & 7;
    const int p0  = (blockIdx.x >> 3) * BN;
    const int tid = threadIdx.x;
    const int lane = tid & 63;
    const int wv   = tid >> 6;
    const int quad = lane >> 4;
    const int l16  = lane & 15;
    const int moff = wv * 32;

    const int px  = tid >> 3;          // sampler: 8 threads/pixel
    const int sub = tid & 7;
    const int hh_ = sub >> 2;
    const int cc_ = (sub & 3) * 8;

    const char* xtb = (const char*)xt + (size_t)b * Pp * Cc * 2;

    // ---- taps for all 9 kernel points ----
    for (int t = tid; t < NK2 * BN; t += 512) {
        int k2 = t >> 6, pxl = t & 63;
        int pl = p0 + pxl;
        int hh = pl >> 6, ww = pl & 63;
        int ky = k2 / 3, kx = k2 - ky * 3;
        float dy = off[((size_t)(b * 18 + 2 * k2    ) * Pp) + pl];
        float dx = off[((size_t)(b * 18 + 2 * k2 + 1) * Pp) + pl];
        float py  = (float)(hh - 1 + ky) + dy;
        float pxf = (float)(ww - 1 + kx) + dx;
        float y0f = floorf(py), x0f = floorf(pxf);
        int   y0 = (int)y0f,  x0 = (int)x0f;
        int   y1 = y0 + 1,    x1 = x0 + 1;
        float ly = py - y0f,  lx = pxf - x0f;
        float oy = 1.f - ly,  ox = 1.f - lx;
        bool vy0 = (y0 >= 0) && (y0 < Hh);
        bool vy1 = (y1 >= 0) && (y1 < Hh);
        bool vx0 = (x0 >= 0) && (x0 < Ww);
        bool vx1 = (x1 >= 0) && (x1 < Ww);
        int cy0 = imin(imax(y0, 0), Hh - 1), cy1 = imin(imax(y1, 0), Hh - 1);
        int cx0 = imin(imax(x0, 0), Ww - 1), cx1 = imin(imax(x1, 0), Ww - 1);
        i32x4 ti; f32x4 tw;
        ti[0] = (cy0 * Ww + cx0) * 512;  tw[0] = (vy0 && vx0) ? oy * ox : 0.f;
        ti[1] = (cy0 * Ww + cx1) * 512;  tw[1] = (vy0 && vx1) ? oy * lx : 0.f;
        ti[2] = (cy1 * Ww + cx0) * 512;  tw[2] = (vy1 && vx0) ? ly * ox : 0.f;
        ti[3] = (cy1 * Ww + cx1) * 512;  tw[3] = (vy1 && vx1) ? ly * lx : 0.f;
        *(i32x4*)&tidx[k2][pxl][0] = ti;
        *(f32x4*)&twgt[k2][pxl][0] = tw;
    }
    barrier_lds();

    int   tio[4];
    float twv[4];
    uint4 g[4];
    {
        i32x4 ti = *(const i32x4*)&tidx[0][px][0];
        f32x4 tw = *(const f32x4*)&twgt[0][px][0];
        #pragma unroll
        for (int t = 0; t < 4; t++) { tio[t] = ti[t]; twv[t] = tw[t]; }
    }

    f32x4 acc[2][4];
    #pragma unroll
    for (int mt = 0; mt < 2; mt++)
        #pragma unroll
        for (int nt = 0; nt < 4; nt++) acc[mt][nt] = (f32x4){0.f, 0.f, 0.f, 0.f};

    // reduce gathered taps (in g) -> pack bf16 -> store into Sl[prn&1]
    auto reduce_store = [&](int prn) {
        float s0 = 0.f, s1 = 0.f, s2 = 0.f, s3 = 0.f, s4 = 0.f, s5 = 0.f, s6 = 0.f, s7 = 0.f;
        #pragma unroll
        for (int t = 0; t < 4; t++) {
            uint4 v = g[t];
            float wg = twv[t];
            s0 += wg * __uint_as_float(v.x << 16);
            s1 += wg * __uint_as_float(v.x);          // low bits = mantissa noise <2^-8
            s2 += wg * __uint_as_float(v.y << 16);
            s3 += wg * __uint_as_float(v.y);
            s4 += wg * __uint_as_float(v.z << 16);
            s5 += wg * __uint_as_float(v.z);
            s6 += wg * __uint_as_float(v.w << 16);
            s7 += wg * __uint_as_float(v.w);
        }
        uint4 d;
        d.x = __builtin_amdgcn_perm(__float_as_uint(s1), __float_as_uint(s0), 0x07060302u);
        d.y = __builtin_amdgcn_perm(__float_as_uint(s3), __float_as_uint(s2), 0x07060302u);
        d.z = __builtin_amdgcn_perm(__float_as_uint(s5), __float_as_uint(s4), 0x07060302u);
        d.w = __builtin_amdgcn_perm(__float_as_uint(s7), __float_as_uint(s6), 0x07060302u);
        *(uint4*)&Sl[prn & 1][hh_][px][cc_] = d;
    };

    s16x8 afA[2][2], afB[2][2];

    // one pipelined K-pair step: consume `cur` + Sl[pr&1]; prefetch pair pr+1
    auto step = [&](int pr, s16x8 (&cur)[2][2], s16x8 (&nxt)[2][2]) {
        barrier_lds();                         // Sl[pr&1] visible; NO vmcnt drain:
                                               // nxt/A loads stay in flight
        const int prn = pr + 1;
        if (prn < NPAIR) {
            if ((prn & 3) == 0) {              // new kernel point: reload taps
                int k2 = prn >> 2;
                i32x4 ti = *(const i32x4*)&tidx[k2][px][0];
                f32x4 tw = *(const f32x4*)&twgt[k2][px][0];
                #pragma unroll
                for (int t = 0; t < 4; t++) { tio[t] = ti[t]; twv[t] = tw[t]; }
            }
            const int coff = (prn & 3) * 128 + sub * 16;
            #pragma unroll
            for (int t = 0; t < 4; t++)        // gathers first (oldest in vm queue)
                g[t] = *(const uint4*)(xtb + tio[t] + coff);
            const char* wb = (const char*)wt + ((size_t)prn << 15);
            #pragma unroll
            for (int h = 0; h < 2; h++)        // A-prefetch for pr+1
                #pragma unroll
                for (int mt = 0; mt < 2; mt++)
                    nxt[h][mt] = *(const s16x8*)(wb + h * 16384 +
                                                 (moff + mt * 16 + l16) * 64 + quad * 16);
        }
        // B fragments + MFMA on current buffer (overlaps the loads above)
        s16x8 bfr[2][4];
        const char* sb = (const char*)&Sl[pr & 1][0][0][0];
        #pragma unroll
        for (int h = 0; h < 2; h++)
            #pragma unroll
            for (int nt = 0; nt < 4; nt++)
                bfr[h][nt] = *(const s16x8*)(sb + h * (BN * SROW * 2) +
                                             (nt * 16 + l16) * (SROW * 2) + quad * 16);
        #pragma unroll
        for (int h = 0; h < 2; h++)
            #pragma unroll
            for (int mt = 0; mt < 2; mt++)
                #pragma unroll
                for (int nt = 0; nt < 4; nt++)
                    acc[mt][nt] = __builtin_amdgcn_mfma_f32_16x16x32_bf16(
                        cur[h][mt], bfr[h][nt], acc[mt][nt], 0, 0, 0);
        if (prn < NPAIR) reduce_store(prn);    // waits on gathers only
    };

    // preamble: gathers + A for pair 0; build Sl[0]
    {
        #pragma unroll
        for (int t = 0; t < 4; t++)
            g[t] = *(const uint4*)(xtb + tio[t] + sub * 16);
        const char* wb = (const char*)wt;
        #pragma unroll
        for (int h = 0; h < 2; h++)
            #pragma unroll
            for (int mt = 0; mt < 2; mt++)
                afA[h][mt] = *(const s16x8*)(wb + h * 16384 +
                                             (moff + mt * 16 + l16) * 64 + quad * 16);
        reduce_store(0);
    }

    for (int pr = 0; pr < NPAIR; pr += 2) {
        step(pr,     afA, afB);
        step(pr + 1, afB, afA);
    }

    // epilogue: C/D layout row(m)=quad*4+r, col(n)=l16
    float* op = out + ((size_t)b * Oo) * Pp + p0;
    #pragma unroll
    for (int mt = 0; mt < 2; mt++)
        #pragma unroll
        for (int nt = 0; nt < 4; nt++)
            #pragma unroll
            for (int r = 0; r < 4; r++) {
                int o_ = moff + mt * 16 + quad * 4 + r;
                int p_ = nt * 16 + l16;
                op[(size_t)o_ * Pp + p_] = acc[mt][nt][r];
            }
}

extern "C" void kernel_launch(void* const* d_in, const int* in_sizes, int n_in,
                              void* d_out, int out_size, void* d_ws, size_t ws_size,
                              hipStream_t stream) {
    (void)in_sizes; (void)n_in; (void)out_size; (void)ws_size;
    const float* x   = (const float*)d_in[0];
    const float* off = (const float*)d_in[1];
    const float* w   = (const float*)d_in[2];
    float* out = (float*)d_out;

    unsigned short* wt = (unsigned short*)d_ws;
    unsigned short* xt = (unsigned short*)((char*)d_ws + WT_BYTES);

    hipLaunchKernelGGL(prep, dim3(2112), dim3(256), 0, stream, x, w, xt, wt);
    hipLaunchKernelGGL(dcn_main, dim3(512), dim3(512), 0, stream, off, wt, xt, out);
}